// Round 6
// baseline (2066.577 us; speedup 1.0000x reference)
//
#include <hip/hip_runtime.h>
#include <hip/hip_bf16.h>

// ---------------------------------------------------------------------------
// KimiDeltaAttention — round 6.
//  * scan v4: 256 blocks, lane=(col 0..15, sl 0..3), s[32]/lane, batched
//    ds_read_b128, DPP quad_perm reductions (no LDS-pipe shuffles).
//  * q/k/v/g in ONE z=4 bf16 MFMA launch; weight compose in bf16 MFMA.
//  * norm_gate writes bf16 directly (fused cast).
// ---------------------------------------------------------------------------

using short8 = __attribute__((ext_vector_type(8))) short;
using f32x4  = __attribute__((ext_vector_type(4))) float;

static __device__ __forceinline__ ushort f2bf(float f) {
    __hip_bfloat16 h = __float2bfloat16(f);
    return *reinterpret_cast<ushort*>(&h);
}

// DPP quad-perm butterfly adds (VALU-speed, no LDS pipe)
static __device__ __forceinline__ float qadd1(float x) {
    int y = __builtin_amdgcn_mov_dpp(__float_as_int(x), 0xB1, 0xF, 0xF, true);
    return x + __int_as_float(y);
}
static __device__ __forceinline__ float qadd2(float x) {
    int y = __builtin_amdgcn_mov_dpp(__float_as_int(x), 0x4E, 0xF, 0xF, true);
    return x + __int_as_float(y);
}

// ----------------------- row-major f32 -> bf16 cast -------------------------
__global__ __launch_bounds__(256) void cast_bf16(const float* __restrict__ in,
                                                 ushort* __restrict__ out, int n8)
{
    const int i = blockIdx.x * 256 + threadIdx.x;
    if (i >= n8) return;
    const float4 a = ((const float4*)in)[2 * i];
    const float4 b = ((const float4*)in)[2 * i + 1];
    ushort u[8] = {f2bf(a.x), f2bf(a.y), f2bf(a.z), f2bf(a.w),
                   f2bf(b.x), f2bf(b.y), f2bf(b.z), f2bf(b.w)};
    ((uint4*)out)[i] = *(uint4*)u;
}

// ------------------- transpose-cast: f32 [R,C] -> bf16 [C,R] ----------------
__global__ __launch_bounds__(256) void tcast(const float* __restrict__ in,
                                             ushort* __restrict__ out,
                                             int R, int C)
{
    __shared__ float tile[64][68];
    const int t  = threadIdx.x;
    const int c0 = blockIdx.x * 64, r0 = blockIdx.y * 64;
    const int lr = t >> 2, lc = (t & 3) * 16;
#pragma unroll
    for (int j = 0; j < 4; ++j) {
        const float4 v = *(const float4*)&in[(size_t)(r0 + lr) * C + c0 + lc + 4 * j];
        *(float4*)&tile[lr][lc + 4 * j] = v;
    }
    __syncthreads();
    const int oc = t >> 2, och = (t & 3) * 16;
    uint u[8];
#pragma unroll
    for (int j = 0; j < 8; ++j) {
        const float f0 = tile[och + 2 * j][oc];
        const float f1 = tile[och + 2 * j + 1][oc];
        u[j] = (uint)f2bf(f0) | ((uint)f2bf(f1) << 16);
    }
    uint4* dst = (uint4*)&out[(size_t)(c0 + oc) * R + r0 + och];
    dst[0] = make_uint4(u[0], u[1], u[2], u[3]);
    dst[1] = make_uint4(u[4], u[5], u[6], u[7]);
}

// --------------- bf16 MFMA GEMM: C[M,N] = A[M,K] @ Bt[N,K]^T ----------------
// 128x128 tile, BK=64, 4 waves (2x2), wave-tile 64x64 = 4x4 mfma 16x16x32.
// z selects one of up to 4 (A,B,C) triples. OUT16: write bf16 C.
template<bool OUT16>
__global__ __launch_bounds__(256) void gemm_bf16(
    const ushort* __restrict__ A0, const ushort* __restrict__ A1,
    const ushort* __restrict__ A2, const ushort* __restrict__ A3,
    const ushort* __restrict__ B0, const ushort* __restrict__ B1,
    const ushort* __restrict__ B2, const ushort* __restrict__ B3,
    void* __restrict__ C0, void* __restrict__ C1,
    void* __restrict__ C2, void* __restrict__ C3,
    int M, int N, int K)
{
    const int z = blockIdx.z;
    const ushort* A = (z == 0) ? A0 : (z == 1) ? A1 : (z == 2) ? A2 : A3;
    const ushort* B = (z == 0) ? B0 : (z == 1) ? B1 : (z == 2) ? B2 : B3;
    void* Cv       = (z == 0) ? C0 : (z == 1) ? C1 : (z == 2) ? C2 : C3;

    __shared__ ushort As[128 * 64];
    __shared__ ushort Bs[128 * 64];

    const int tid  = threadIdx.x;
    const int lane = tid & 63;
    const int wave = tid >> 6;
    const int wm = wave >> 1, wn = wave & 1;
    const int bm = blockIdx.x * 128, bn = blockIdx.y * 128;

    const int srow  = tid >> 1;
    const int spart = tid & 1;

    const int ml = lane & 15;
    const int g  = lane >> 4;

    f32x4 acc[4][4];
#pragma unroll
    for (int i = 0; i < 4; ++i)
#pragma unroll
        for (int j = 0; j < 4; ++j) acc[i][j] = (f32x4){0.f, 0.f, 0.f, 0.f};

    const size_t arow_off = (size_t)(bm + srow) * K;
    const size_t brow_off = (size_t)(bn + srow) * K;

    for (int k0 = 0; k0 < K; k0 += 64) {
#pragma unroll
        for (int j = 0; j < 4; ++j) {
            const int ch = spart * 4 + j;
            const int sw = ((srow * 128 + ch * 16) ^ ((srow & 7) << 4)) >> 1;
            *(uint4*)&As[sw] = *(const uint4*)&A[arow_off + k0 + ch * 8];
            *(uint4*)&Bs[sw] = *(const uint4*)&B[brow_off + k0 + ch * 8];
        }
        __syncthreads();
#pragma unroll
        for (int kk = 0; kk < 2; ++kk) {
            short8 af[4], bfr[4];
#pragma unroll
            for (int mi = 0; mi < 4; ++mi) {
                const int row = wm * 64 + mi * 16 + ml;
                const int sw  = ((row * 128 + (kk * 4 + g) * 16) ^ ((ml & 7) << 4)) >> 1;
                af[mi] = *(const short8*)&As[sw];
            }
#pragma unroll
            for (int ni = 0; ni < 4; ++ni) {
                const int row = wn * 64 + ni * 16 + ml;
                const int sw  = ((row * 128 + (kk * 4 + g) * 16) ^ ((ml & 7) << 4)) >> 1;
                bfr[ni] = *(const short8*)&Bs[sw];
            }
#pragma unroll
            for (int mi = 0; mi < 4; ++mi)
#pragma unroll
                for (int ni = 0; ni < 4; ++ni)
                    acc[mi][ni] = __builtin_amdgcn_mfma_f32_16x16x32_bf16(
                        af[mi], bfr[ni], acc[mi][ni], 0, 0, 0);
        }
        __syncthreads();
    }

#pragma unroll
    for (int mi = 0; mi < 4; ++mi)
#pragma unroll
        for (int ni = 0; ni < 4; ++ni) {
            const int col = bn + wn * 64 + ni * 16 + ml;
#pragma unroll
            for (int r = 0; r < 4; ++r) {
                const int row = bm + wm * 64 + mi * 16 + g * 4 + r;
                if constexpr (OUT16) {
                    ((ushort*)Cv)[(size_t)row * N + col] = f2bf(acc[mi][ni][r]);
                } else {
                    ((float*)Cv)[(size_t)row * N + col] = acc[mi][ni][r];
                }
            }
        }
}

// ------------------- small-N GEMM for beta: N = 16 -------------------------
__global__ __launch_bounds__(256) void gemm_n16(
    const float* __restrict__ A, const float* __restrict__ B,
    float* __restrict__ C, int M, int Kd)
{
    const int tid  = threadIdx.x;
    const int n    = tid & 15;
    const int mloc = tid >> 4;
    const int m    = blockIdx.x * 16 + mloc;
    const float* a  = A + (size_t)m * Kd;
    const float* bn = B + n;
    float acc = 0.f;
#pragma unroll 4
    for (int k0 = 0; k0 < Kd; k0 += 8) {
        float4 a0 = *(const float4*)(a + k0);
        float4 a1 = *(const float4*)(a + k0 + 4);
        acc = fmaf(a0.x, bn[(size_t)(k0 + 0) * 16], acc);
        acc = fmaf(a0.y, bn[(size_t)(k0 + 1) * 16], acc);
        acc = fmaf(a0.z, bn[(size_t)(k0 + 2) * 16], acc);
        acc = fmaf(a0.w, bn[(size_t)(k0 + 3) * 16], acc);
        acc = fmaf(a1.x, bn[(size_t)(k0 + 4) * 16], acc);
        acc = fmaf(a1.y, bn[(size_t)(k0 + 5) * 16], acc);
        acc = fmaf(a1.z, bn[(size_t)(k0 + 6) * 16], acc);
        acc = fmaf(a1.w, bn[(size_t)(k0 + 7) * 16], acc);
    }
    C[(size_t)m * 16 + n] = acc;
}

// ---- halo save: pre-conv values at segment boundaries (race-free split) ----
__global__ __launch_bounds__(256) void halo_save(
    const float* __restrict__ q, const float* __restrict__ k,
    const float* __restrict__ v, float* __restrict__ hal)
{
    constexpr int T = 2048, C = 2048, SEG = 512;
    const int idx = blockIdx.x * 256 + threadIdx.x;   // < 9*12288
    const int cid = idx % 12288;
    const int sh  = idx / 12288;      // 0..8
    const int sg  = sh / 3 + 1;       // segment 1..3
    const int ho  = sh % 3;           // halo offset 0..2
    const int which = cid >> 12, rem = cid & 4095, b = rem >> 11, c = rem & 2047;
    const float* x = (which == 0) ? q : (which == 1) ? k : v;
    hal[idx] = x[(size_t)b * T * C + (size_t)(sg * SEG - 3 + ho) * C + c];
}

// ------- depthwise causal conv (K=4) + SiLU, in-place, 4 T-segments ---------
__global__ __launch_bounds__(256) void conv_silu(
    float* __restrict__ q, float* __restrict__ k, float* __restrict__ v,
    const float* __restrict__ wq, const float* __restrict__ wk,
    const float* __restrict__ wv, const float* __restrict__ hal)
{
    constexpr int T = 2048, C = 2048, SEG = 512;
    const int seg    = blockIdx.x & 3;
    const int colblk = blockIdx.x >> 2;
    const int cid    = colblk * 256 + threadIdx.x;
    const int which  = cid >> 12;
    const int rem    = cid & 4095;
    const int b      = rem >> 11;
    const int c      = rem & 2047;
    float* x        = (which == 0) ? q : (which == 1) ? k : v;
    const float* w  = (which == 0) ? wq : (which == 1) ? wk : wv;

    const float w0 = w[c * 4 + 0], w1 = w[c * 4 + 1];
    const float w2 = w[c * 4 + 2], w3 = w[c * 4 + 3];
    float* p = x + (size_t)b * T * C + c;
    float xm3, xm2, xm1;
    if (seg == 0) { xm3 = xm2 = xm1 = 0.f; }
    else {
        xm3 = hal[((seg - 1) * 3 + 0) * 12288 + cid];
        xm2 = hal[((seg - 1) * 3 + 1) * 12288 + cid];
        xm1 = hal[((seg - 1) * 3 + 2) * 12288 + cid];
    }

    const int t0s = seg * SEG;
    for (int t0 = t0s; t0 < t0s + SEG; t0 += 16) {
        float xt[16], yo[16];
#pragma unroll
        for (int j = 0; j < 16; ++j) xt[j] = p[(size_t)(t0 + j) * C];
#pragma unroll
        for (int j = 0; j < 16; ++j) {
            float y = fmaf(xm3, w0, fmaf(xm2, w1, fmaf(xm1, w2, xt[j] * w3)));
            yo[j] = y / (1.f + __expf(-y));
            xm3 = xm2; xm2 = xm1; xm1 = xt[j];
        }
#pragma unroll
        for (int j = 0; j < 16; ++j) p[(size_t)(t0 + j) * C] = yo[j];
    }
}

// ------ prep: l2norm(q)*D^-0.5, l2norm(k), g -> exp(-exp(A_log)*softplus) ---
__global__ __launch_bounds__(256) void prep_qkg(
    float* __restrict__ Qb, float* __restrict__ Kb, float* __restrict__ Gb,
    const float* __restrict__ A_log, const float* __restrict__ dt_bias,
    int rows)
{
    const int wave = threadIdx.x >> 6;
    const int lane = threadIdx.x & 63;
    const int row  = blockIdx.x * 4 + wave;
    if (row >= rows) return;
    const int hh = row & 15;
    const size_t base = (size_t)row * 128;

    float q0 = Qb[base + lane], q1 = Qb[base + 64 + lane];
    float k0 = Kb[base + lane], k1 = Kb[base + 64 + lane];
    float sq = q0 * q0 + q1 * q1;
    float sk = k0 * k0 + k1 * k1;
#pragma unroll
    for (int off = 32; off >= 1; off >>= 1) {
        sq += __shfl_xor(sq, off);
        sk += __shfl_xor(sk, off);
    }
    const float qs = rsqrtf(sq + 1e-6f) * 0.08838834764831845f;
    const float ks = rsqrtf(sk + 1e-6f);
    Qb[base + lane] = q0 * qs; Qb[base + 64 + lane] = q1 * qs;
    Kb[base + lane] = k0 * ks; Kb[base + 64 + lane] = k1 * ks;

    const float a = __expf(A_log[hh]);
    float x0 = Gb[base + lane]      + dt_bias[hh * 128 + lane];
    float x1 = Gb[base + 64 + lane] + dt_bias[hh * 128 + 64 + lane];
    float sp0 = (x0 > 20.f) ? x0 : log1pf(__expf(x0));
    float sp1 = (x1 > 20.f) ? x1 : log1pf(__expf(x1));
    Gb[base + lane]      = __expf(-a * sp0);
    Gb[base + 64 + lane] = __expf(-a * sp1);
}

// --------------------- gated delta-rule sequential scan ---------------------
// 256 blocks = (vg 0..7) x (b,h 0..31); 1 wave; lane = (col 0..15, sl 0..3).
// s[32]/lane; 24 batched ds_read_b128 (broadcast, chunk-perm c^(c>>3));
// reductions = DPP quad_perm xor1+xor2 (pure VALU); 2-step global prefetch.
__global__ __launch_bounds__(64) void kda_scan(
    const float* __restrict__ Q, const float* __restrict__ Kk,
    const float* __restrict__ V, const float* __restrict__ EG,
    const float* __restrict__ Braw, float* __restrict__ O)
{
    constexpr int T = 2048, H = 16, HD = 2048;
    const int bid = blockIdx.x;
    const int bh  = bid & 31;          // same (b,h) -> same XCD (stride 32 ≡ 0 mod 8)
    const int vg  = bid >> 5;          // 0..7
    const int b = bh >> 4, hh = bh & 15;
    const int lane = threadIdx.x;
    const int col  = lane >> 2;        // 0..15
    const int sl   = lane & 3;         // 0..3 (k-slice of 32)
    const int vcol = vg * 16 + col;

    __shared__ __align__(16) float kb_s[2][128];
    __shared__ __align__(16) float eb_s[2][128];
    __shared__ __align__(16) float qb_s[2][128];

    float s[32];
#pragma unroll
    for (int i = 0; i < 32; ++i) s[i] = 0.f;

    const size_t tok0 = (size_t)b * T;
    const int cb = hh * 128;
    const float* qp = Q  + tok0 * HD + cb;
    const float* kp = Kk + tok0 * HD + cb;
    const float* ep = EG + tok0 * HD + cb;
    const float* vp = V  + tok0 * HD + cb;
    const float* bp = Braw + tok0 * H + hh;
    float* op = O + tok0 * HD + cb;

    // write position: lane stages float2 of chunk cw = lane>>1 at perm pos
    const int d0 = 2 * lane;
    const int cw = lane >> 1;
    const int pw = cw ^ (cw >> 3);
    const int stpos = pw * 4 + (d0 & 3);

    // read offsets: chunk c = 8*sl + j stored at c ^ sl  ((c>>3)==sl)
    int rof[8];
#pragma unroll
    for (int j = 0; j < 8; ++j) rof[j] = (((sl << 3) + j) ^ sl) << 2;

    // prologue: stage t=0, prefetch t=1
    *(float2*)&kb_s[0][stpos] = *(const float2*)&kp[d0];
    *(float2*)&eb_s[0][stpos] = *(const float2*)&ep[d0];
    *(float2*)&qb_s[0][stpos] = *(const float2*)&qp[d0];
    float rv  = vp[vcol];
    float rb  = bp[0];
    float2 pk = *(const float2*)&kp[HD + d0];
    float2 pe = *(const float2*)&ep[HD + d0];
    float2 pq = *(const float2*)&qp[HD + d0];
    float rv1 = vp[HD + vcol];
    float rb1 = bp[H];

    for (int t = 0; t < T; ++t) {
        const int cur = t & 1, nxt = cur ^ 1;
        if (t + 1 < T) {                    // write staged t+1 (other buffer)
            *(float2*)&kb_s[nxt][stpos] = pk;
            *(float2*)&eb_s[nxt][stpos] = pe;
            *(float2*)&qb_s[nxt][stpos] = pq;
        }
        float2 nk{}, ne{}, nq{}; float nv = 0.f, nb = 0.f;
        if (t + 2 < T) {                    // prefetch t+2
            const size_t o2 = (size_t)(t + 2) * HD;
            nk = *(const float2*)&kp[o2 + d0];
            ne = *(const float2*)&ep[o2 + d0];
            nq = *(const float2*)&qp[o2 + d0];
            nv = vp[o2 + vcol];
            nb = bp[(size_t)(t + 2) * H];
        }
        const float beta = 1.f / (1.f + __expf(-rb));

        // batched LDS reads: one latency exposure for all 24 b128 reads
        float4 er[8], kr[8], qr[8];
#pragma unroll
        for (int j = 0; j < 8; ++j) {
            er[j] = *(const float4*)&eb_s[cur][rof[j]];
            kr[j] = *(const float4*)&kb_s[cur][rof[j]];
            qr[j] = *(const float4*)&qb_s[cur][rof[j]];
        }

        // pass 1: decay + in-slice k.s
        float a0 = 0.f, a1 = 0.f, a2 = 0.f, a3 = 0.f;
#pragma unroll
        for (int j = 0; j < 8; ++j) {
            float s0 = s[4 * j + 0] * er[j].x, s1 = s[4 * j + 1] * er[j].y;
            float s2 = s[4 * j + 2] * er[j].z, s3 = s[4 * j + 3] * er[j].w;
            s[4 * j + 0] = s0; s[4 * j + 1] = s1;
            s[4 * j + 2] = s2; s[4 * j + 3] = s3;
            a0 = fmaf(kr[j].x, s0, a0); a1 = fmaf(kr[j].y, s1, a1);
            a2 = fmaf(kr[j].z, s2, a2); a3 = fmaf(kr[j].w, s3, a3);
        }
        float kS = (a0 + a1) + (a2 + a3);
        kS = qadd1(kS);
        kS = qadd2(kS);                     // full sum across sl 0..3
        const float delta = beta * (rv - kS);

        // pass 2: rank-1 update + in-slice q.s
        float o0 = 0.f, o1 = 0.f, o2v = 0.f, o3 = 0.f;
#pragma unroll
        for (int j = 0; j < 8; ++j) {
            float s0 = fmaf(kr[j].x, delta, s[4 * j + 0]);
            float s1 = fmaf(kr[j].y, delta, s[4 * j + 1]);
            float s2 = fmaf(kr[j].z, delta, s[4 * j + 2]);
            float s3 = fmaf(kr[j].w, delta, s[4 * j + 3]);
            s[4 * j + 0] = s0; s[4 * j + 1] = s1;
            s[4 * j + 2] = s2; s[4 * j + 3] = s3;
            o0 = fmaf(qr[j].x, s0, o0); o1 = fmaf(qr[j].y, s1, o1);
            o2v = fmaf(qr[j].z, s2, o2v); o3 = fmaf(qr[j].w, s3, o3);
        }
        float oo = (o0 + o1) + (o2v + o3);
        oo = qadd1(oo);
        oo = qadd2(oo);
        if (sl == 0) op[(size_t)t * HD + vcol] = oo;

        rv = rv1; rb = rb1; rv1 = nv; rb1 = nb;
        pk = nk; pe = ne; pq = nq;
    }
}

// ------ gated RMSNorm: obf16 = rms(o)*norm_w*sigmoid(gate), bf16 out --------
__global__ __launch_bounds__(256) void norm_gate(
    const float* __restrict__ O, const float* __restrict__ Gate,
    const float* __restrict__ norm_w, ushort* __restrict__ Out16, int rows)
{
    const int wave = threadIdx.x >> 6;
    const int lane = threadIdx.x & 63;
    const int row  = blockIdx.x * 4 + wave;
    if (row >= rows) return;
    const size_t base = (size_t)row * 128;

    float o0 = O[base + lane], o1 = O[base + 64 + lane];
    float ss = o0 * o0 + o1 * o1;
#pragma unroll
    for (int off = 32; off >= 1; off >>= 1) ss += __shfl_xor(ss, off);
    const float scale = rsqrtf(ss * (1.f / 128.f) + 1e-6f);

    const float g0 = Gate[base + lane], g1 = Gate[base + 64 + lane];
    o0 = o0 * scale * norm_w[lane]      * (1.f / (1.f + __expf(-g0)));
    o1 = o1 * scale * norm_w[64 + lane] * (1.f / (1.f + __expf(-g1)));
    Out16[base + lane]      = f2bf(o0);
    Out16[base + 64 + lane] = f2bf(o1);
}

// ---------------------------------------------------------------------------
extern "C" void kernel_launch(void* const* d_in, const int* in_sizes, int n_in,
                              void* d_out, int out_size, void* d_ws, size_t ws_size,
                              hipStream_t stream)
{
    const float* h    = (const float*)d_in[0];
    const float* Wq   = (const float*)d_in[1];
    const float* Wk   = (const float*)d_in[2];
    const float* Wv   = (const float*)d_in[3];
    const float* cwq  = (const float*)d_in[4];
    const float* cwk  = (const float*)d_in[5];
    const float* cwv  = (const float*)d_in[6];
    const float* A_log= (const float*)d_in[7];
    const float* dtb  = (const float*)d_in[8];
    const float* Wfa  = (const float*)d_in[9];
    const float* Wfb  = (const float*)d_in[10];
    const float* Wb   = (const float*)d_in[11];
    const float* Wga  = (const float*)d_in[12];
    const float* Wgb  = (const float*)d_in[13];
    const float* nw   = (const float*)d_in[14];
    const float* Wo   = (const float*)d_in[15];
    float* out = (float*)d_out;

    const int M = 4096, HID = 2048;
    const size_t big = (size_t)M * HID;        // 8M elements
    float* ws    = (float*)d_ws;
    float* qb    = ws;          // post-scan: gateb
    float* kb    = qb + big;
    float* vb    = kb + big;    // post-norm: obb16 (ushort)
    float* gb    = vb + big;
    float* ob    = gb + big;
    float* betab = ob + big;                        // 4096x16
    float* halb  = betab + (size_t)M * 16;          // 110592
    ushort* hb16 = (ushort*)(halb + 110592);        // [M,HID] bf16
    ushort* wqT  = hb16 + big;                      // [2048,2048] bf16 (x4)
    ushort* wkT  = wqT + (size_t)HID * HID;
    ushort* wvT  = wkT + (size_t)HID * HID;
    ushort* wfT  = wvT + (size_t)HID * HID;
    ushort* tfbT = wfT + (size_t)HID * HID;         // [2048,128] bf16
    ushort* wfa16= tfbT + (size_t)HID * 128;        // [2048,128] bf16

    float*  gateb = qb;
    ushort* obb16 = (ushort*)vb;

    dim3 blk(256);

    // bf16 casts / transposes
    cast_bf16<<<dim3(4096), blk, 0, stream>>>(h, hb16, (int)(big / 8));
    tcast<<<dim3(32, 32), blk, 0, stream>>>(Wq, wqT, HID, HID);
    tcast<<<dim3(32, 32), blk, 0, stream>>>(Wk, wkT, HID, HID);
    tcast<<<dim3(32, 32), blk, 0, stream>>>(Wv, wvT, HID, HID);

    // compose Wf = Wfa@Wfb in bf16 MFMA: wfT[m,n] = sum_k Wfb[k,m]*Wfa[n,k]
    tcast<<<dim3(32, 2), blk, 0, stream>>>(Wfb, tfbT, 128, HID);
    cast_bf16<<<dim3(128), blk, 0, stream>>>(Wfa, wfa16, (int)((size_t)HID * 128 / 8));
    gemm_bf16<true><<<dim3(16, 16, 1), blk, 0, stream>>>(
        tfbT, tfbT, tfbT, tfbT, wfa16, wfa16, wfa16, wfa16,
        wfT, wfT, wfT, wfT, HID, HID, 128);

    // q,k,v,g projections in ONE launch
    gemm_bf16<false><<<dim3(32, 16, 4), blk, 0, stream>>>(
        hb16, hb16, hb16, hb16, wqT, wkT, wvT, wfT,
        qb, kb, vb, gb, M, HID, HID);

    // beta
    gemm_n16<<<dim3(M / 16), blk, 0, stream>>>(h, Wb, betab, M, HID);

    // conv + SiLU (segmented, race-free via halo snapshot)
    halo_save<<<dim3(432), blk, 0, stream>>>(qb, kb, vb, halb);
    conv_silu<<<dim3(192), blk, 0, stream>>>(qb, kb, vb, cwq, cwk, cwv, halb);

    // l2norm q/k, g -> exp(g)
    prep_qkg<<<dim3(16384), blk, 0, stream>>>(qb, kb, gb, A_log, dtb, M * 16);

    // gated delta-rule scan
    kda_scan<<<dim3(256), dim3(64), 0, stream>>>(qb, kb, vb, gb, betab, ob);

    // gate path: compose Wg = Wga@Wgb (bf16 MFMA, reuse small scratch + wqT)
    tcast<<<dim3(32, 2), blk, 0, stream>>>(Wgb, tfbT, 128, HID);
    cast_bf16<<<dim3(128), blk, 0, stream>>>(Wga, wfa16, (int)((size_t)HID * 128 / 8));
    gemm_bf16<true><<<dim3(16, 16, 1), blk, 0, stream>>>(
        tfbT, tfbT, tfbT, tfbT, wfa16, wfa16, wfa16, wfa16,
        wqT, wqT, wqT, wqT, HID, HID, 128);
    gemm_bf16<false><<<dim3(32, 16, 1), blk, 0, stream>>>(
        hb16, hb16, hb16, hb16, wqT, wqT, wqT, wqT,
        gateb, gateb, gateb, gateb, M, HID, HID);

    // gated RMSNorm -> bf16 (fused cast)
    norm_gate<<<dim3(16384), blk, 0, stream>>>(ob, gateb, nw, obb16, M * 16);

    // output projection
    tcast<<<dim3(32, 32), blk, 0, stream>>>(Wo, wkT, HID, HID);
    gemm_bf16<false><<<dim3(32, 16, 1), blk, 0, stream>>>(
        obb16, obb16, obb16, obb16, wkT, wkT, wkT, wkT,
        out, out, out, out, M, HID, HID);
}

// Round 7
// 1635.738 us; speedup vs baseline: 1.2634x; 1.2634x over previous
//
#include <hip/hip_runtime.h>
#include <hip/hip_bf16.h>

// ---------------------------------------------------------------------------
// KimiDeltaAttention — round 7.
//  * scan v5: depth-3 global register FIFO (loads for t+3, 2-step vmcnt gap),
//    precomputed beta, batched ds_read_b128, DPP quad reductions, unroll x2.
//  * q/k/v/g in ONE z=4 bf16 MFMA launch; weight compose in bf16 MFMA.
//  * norm_gate writes bf16 directly (fused cast).
// ---------------------------------------------------------------------------

using short8 = __attribute__((ext_vector_type(8))) short;
using f32x4  = __attribute__((ext_vector_type(4))) float;

static __device__ __forceinline__ ushort f2bf(float f) {
    __hip_bfloat16 h = __float2bfloat16(f);
    return *reinterpret_cast<ushort*>(&h);
}

// DPP quad-perm butterfly adds (VALU-speed, no LDS pipe)
static __device__ __forceinline__ float qadd1(float x) {
    int y = __builtin_amdgcn_mov_dpp(__float_as_int(x), 0xB1, 0xF, 0xF, true);
    return x + __int_as_float(y);
}
static __device__ __forceinline__ float qadd2(float x) {
    int y = __builtin_amdgcn_mov_dpp(__float_as_int(x), 0x4E, 0xF, 0xF, true);
    return x + __int_as_float(y);
}

// ----------------------- row-major f32 -> bf16 cast -------------------------
__global__ __launch_bounds__(256) void cast_bf16(const float* __restrict__ in,
                                                 ushort* __restrict__ out, int n8)
{
    const int i = blockIdx.x * 256 + threadIdx.x;
    if (i >= n8) return;
    const float4 a = ((const float4*)in)[2 * i];
    const float4 b = ((const float4*)in)[2 * i + 1];
    ushort u[8] = {f2bf(a.x), f2bf(a.y), f2bf(a.z), f2bf(a.w),
                   f2bf(b.x), f2bf(b.y), f2bf(b.z), f2bf(b.w)};
    ((uint4*)out)[i] = *(uint4*)u;
}

// ------------------- transpose-cast: f32 [R,C] -> bf16 [C,R] ----------------
__global__ __launch_bounds__(256) void tcast(const float* __restrict__ in,
                                             ushort* __restrict__ out,
                                             int R, int C)
{
    __shared__ float tile[64][68];
    const int t  = threadIdx.x;
    const int c0 = blockIdx.x * 64, r0 = blockIdx.y * 64;
    const int lr = t >> 2, lc = (t & 3) * 16;
#pragma unroll
    for (int j = 0; j < 4; ++j) {
        const float4 v = *(const float4*)&in[(size_t)(r0 + lr) * C + c0 + lc + 4 * j];
        *(float4*)&tile[lr][lc + 4 * j] = v;
    }
    __syncthreads();
    const int oc = t >> 2, och = (t & 3) * 16;
    uint u[8];
#pragma unroll
    for (int j = 0; j < 8; ++j) {
        const float f0 = tile[och + 2 * j][oc];
        const float f1 = tile[och + 2 * j + 1][oc];
        u[j] = (uint)f2bf(f0) | ((uint)f2bf(f1) << 16);
    }
    uint4* dst = (uint4*)&out[(size_t)(c0 + oc) * R + r0 + och];
    dst[0] = make_uint4(u[0], u[1], u[2], u[3]);
    dst[1] = make_uint4(u[4], u[5], u[6], u[7]);
}

// --------------- bf16 MFMA GEMM: C[M,N] = A[M,K] @ Bt[N,K]^T ----------------
template<bool OUT16>
__global__ __launch_bounds__(256) void gemm_bf16(
    const ushort* __restrict__ A0, const ushort* __restrict__ A1,
    const ushort* __restrict__ A2, const ushort* __restrict__ A3,
    const ushort* __restrict__ B0, const ushort* __restrict__ B1,
    const ushort* __restrict__ B2, const ushort* __restrict__ B3,
    void* __restrict__ C0, void* __restrict__ C1,
    void* __restrict__ C2, void* __restrict__ C3,
    int M, int N, int K)
{
    const int z = blockIdx.z;
    const ushort* A = (z == 0) ? A0 : (z == 1) ? A1 : (z == 2) ? A2 : A3;
    const ushort* B = (z == 0) ? B0 : (z == 1) ? B1 : (z == 2) ? B2 : B3;
    void* Cv       = (z == 0) ? C0 : (z == 1) ? C1 : (z == 2) ? C2 : C3;

    __shared__ ushort As[128 * 64];
    __shared__ ushort Bs[128 * 64];

    const int tid  = threadIdx.x;
    const int lane = tid & 63;
    const int wave = tid >> 6;
    const int wm = wave >> 1, wn = wave & 1;
    const int bm = blockIdx.x * 128, bn = blockIdx.y * 128;

    const int srow  = tid >> 1;
    const int spart = tid & 1;

    const int ml = lane & 15;
    const int g  = lane >> 4;

    f32x4 acc[4][4];
#pragma unroll
    for (int i = 0; i < 4; ++i)
#pragma unroll
        for (int j = 0; j < 4; ++j) acc[i][j] = (f32x4){0.f, 0.f, 0.f, 0.f};

    const size_t arow_off = (size_t)(bm + srow) * K;
    const size_t brow_off = (size_t)(bn + srow) * K;

    for (int k0 = 0; k0 < K; k0 += 64) {
#pragma unroll
        for (int j = 0; j < 4; ++j) {
            const int ch = spart * 4 + j;
            const int sw = ((srow * 128 + ch * 16) ^ ((srow & 7) << 4)) >> 1;
            *(uint4*)&As[sw] = *(const uint4*)&A[arow_off + k0 + ch * 8];
            *(uint4*)&Bs[sw] = *(const uint4*)&B[brow_off + k0 + ch * 8];
        }
        __syncthreads();
#pragma unroll
        for (int kk = 0; kk < 2; ++kk) {
            short8 af[4], bfr[4];
#pragma unroll
            for (int mi = 0; mi < 4; ++mi) {
                const int row = wm * 64 + mi * 16 + ml;
                const int sw  = ((row * 128 + (kk * 4 + g) * 16) ^ ((ml & 7) << 4)) >> 1;
                af[mi] = *(const short8*)&As[sw];
            }
#pragma unroll
            for (int ni = 0; ni < 4; ++ni) {
                const int row = wn * 64 + ni * 16 + ml;
                const int sw  = ((row * 128 + (kk * 4 + g) * 16) ^ ((ml & 7) << 4)) >> 1;
                bfr[ni] = *(const short8*)&Bs[sw];
            }
#pragma unroll
            for (int mi = 0; mi < 4; ++mi)
#pragma unroll
                for (int ni = 0; ni < 4; ++ni)
                    acc[mi][ni] = __builtin_amdgcn_mfma_f32_16x16x32_bf16(
                        af[mi], bfr[ni], acc[mi][ni], 0, 0, 0);
        }
        __syncthreads();
    }

#pragma unroll
    for (int mi = 0; mi < 4; ++mi)
#pragma unroll
        for (int ni = 0; ni < 4; ++ni) {
            const int col = bn + wn * 64 + ni * 16 + ml;
#pragma unroll
            for (int r = 0; r < 4; ++r) {
                const int row = bm + wm * 64 + mi * 16 + g * 4 + r;
                if constexpr (OUT16) {
                    ((ushort*)Cv)[(size_t)row * N + col] = f2bf(acc[mi][ni][r]);
                } else {
                    ((float*)Cv)[(size_t)row * N + col] = acc[mi][ni][r];
                }
            }
        }
}

// ------------------- small-N GEMM for beta: N = 16 -------------------------
__global__ __launch_bounds__(256) void gemm_n16(
    const float* __restrict__ A, const float* __restrict__ B,
    float* __restrict__ C, int M, int Kd)
{
    const int tid  = threadIdx.x;
    const int n    = tid & 15;
    const int mloc = tid >> 4;
    const int m    = blockIdx.x * 16 + mloc;
    const float* a  = A + (size_t)m * Kd;
    const float* bn = B + n;
    float acc = 0.f;
#pragma unroll 4
    for (int k0 = 0; k0 < Kd; k0 += 8) {
        float4 a0 = *(const float4*)(a + k0);
        float4 a1 = *(const float4*)(a + k0 + 4);
        acc = fmaf(a0.x, bn[(size_t)(k0 + 0) * 16], acc);
        acc = fmaf(a0.y, bn[(size_t)(k0 + 1) * 16], acc);
        acc = fmaf(a0.z, bn[(size_t)(k0 + 2) * 16], acc);
        acc = fmaf(a0.w, bn[(size_t)(k0 + 3) * 16], acc);
        acc = fmaf(a1.x, bn[(size_t)(k0 + 4) * 16], acc);
        acc = fmaf(a1.y, bn[(size_t)(k0 + 5) * 16], acc);
        acc = fmaf(a1.z, bn[(size_t)(k0 + 6) * 16], acc);
        acc = fmaf(a1.w, bn[(size_t)(k0 + 7) * 16], acc);
    }
    C[(size_t)m * 16 + n] = acc;
}

// ---- halo save: pre-conv values at segment boundaries (race-free split) ----
__global__ __launch_bounds__(256) void halo_save(
    const float* __restrict__ q, const float* __restrict__ k,
    const float* __restrict__ v, float* __restrict__ hal)
{
    constexpr int T = 2048, C = 2048, SEG = 512;
    const int idx = blockIdx.x * 256 + threadIdx.x;   // < 9*12288
    const int cid = idx % 12288;
    const int sh  = idx / 12288;      // 0..8
    const int sg  = sh / 3 + 1;       // segment 1..3
    const int ho  = sh % 3;           // halo offset 0..2
    const int which = cid >> 12, rem = cid & 4095, b = rem >> 11, c = rem & 2047;
    const float* x = (which == 0) ? q : (which == 1) ? k : v;
    hal[idx] = x[(size_t)b * T * C + (size_t)(sg * SEG - 3 + ho) * C + c];
}

// ------- depthwise causal conv (K=4) + SiLU, in-place, 4 T-segments ---------
__global__ __launch_bounds__(256) void conv_silu(
    float* __restrict__ q, float* __restrict__ k, float* __restrict__ v,
    const float* __restrict__ wq, const float* __restrict__ wk,
    const float* __restrict__ wv, const float* __restrict__ hal)
{
    constexpr int T = 2048, C = 2048, SEG = 512;
    const int seg    = blockIdx.x & 3;
    const int colblk = blockIdx.x >> 2;
    const int cid    = colblk * 256 + threadIdx.x;
    const int which  = cid >> 12;
    const int rem    = cid & 4095;
    const int b      = rem >> 11;
    const int c      = rem & 2047;
    float* x        = (which == 0) ? q : (which == 1) ? k : v;
    const float* w  = (which == 0) ? wq : (which == 1) ? wk : wv;

    const float w0 = w[c * 4 + 0], w1 = w[c * 4 + 1];
    const float w2 = w[c * 4 + 2], w3 = w[c * 4 + 3];
    float* p = x + (size_t)b * T * C + c;
    float xm3, xm2, xm1;
    if (seg == 0) { xm3 = xm2 = xm1 = 0.f; }
    else {
        xm3 = hal[((seg - 1) * 3 + 0) * 12288 + cid];
        xm2 = hal[((seg - 1) * 3 + 1) * 12288 + cid];
        xm1 = hal[((seg - 1) * 3 + 2) * 12288 + cid];
    }

    const int t0s = seg * SEG;
    for (int t0 = t0s; t0 < t0s + SEG; t0 += 16) {
        float xt[16], yo[16];
#pragma unroll
        for (int j = 0; j < 16; ++j) xt[j] = p[(size_t)(t0 + j) * C];
#pragma unroll
        for (int j = 0; j < 16; ++j) {
            float y = fmaf(xm3, w0, fmaf(xm2, w1, fmaf(xm1, w2, xt[j] * w3)));
            yo[j] = y / (1.f + __expf(-y));
            xm3 = xm2; xm2 = xm1; xm1 = xt[j];
        }
#pragma unroll
        for (int j = 0; j < 16; ++j) p[(size_t)(t0 + j) * C] = yo[j];
    }
}

// ------ prep: l2norm(q)*D^-0.5, l2norm(k), g -> exp(-exp(A_log)*softplus) ---
__global__ __launch_bounds__(256) void prep_qkg(
    float* __restrict__ Qb, float* __restrict__ Kb, float* __restrict__ Gb,
    const float* __restrict__ A_log, const float* __restrict__ dt_bias,
    int rows)
{
    const int wave = threadIdx.x >> 6;
    const int lane = threadIdx.x & 63;
    const int row  = blockIdx.x * 4 + wave;
    if (row >= rows) return;
    const int hh = row & 15;
    const size_t base = (size_t)row * 128;

    float q0 = Qb[base + lane], q1 = Qb[base + 64 + lane];
    float k0 = Kb[base + lane], k1 = Kb[base + 64 + lane];
    float sq = q0 * q0 + q1 * q1;
    float sk = k0 * k0 + k1 * k1;
#pragma unroll
    for (int off = 32; off >= 1; off >>= 1) {
        sq += __shfl_xor(sq, off);
        sk += __shfl_xor(sk, off);
    }
    const float qs = rsqrtf(sq + 1e-6f) * 0.08838834764831845f;
    const float ks = rsqrtf(sk + 1e-6f);
    Qb[base + lane] = q0 * qs; Qb[base + 64 + lane] = q1 * qs;
    Kb[base + lane] = k0 * ks; Kb[base + 64 + lane] = k1 * ks;

    const float a = __expf(A_log[hh]);
    float x0 = Gb[base + lane]      + dt_bias[hh * 128 + lane];
    float x1 = Gb[base + 64 + lane] + dt_bias[hh * 128 + 64 + lane];
    float sp0 = (x0 > 20.f) ? x0 : log1pf(__expf(x0));
    float sp1 = (x1 > 20.f) ? x1 : log1pf(__expf(x1));
    Gb[base + lane]      = __expf(-a * sp0);
    Gb[base + 64 + lane] = __expf(-a * sp1);
}

// --------------------- gated delta-rule sequential scan ---------------------
// 256 blocks = (vg 0..7) x (b,h 0..31); 1 wave; lane = (col 0..15, sl 0..3).
// s[32]/lane; batched ds_read_b128; DPP quad reductions; depth-3 register
// FIFO: loads issued at t fill t+3, LDS-write consumes at t+2 (2-step vmcnt
// gap ~= 1000 cyc hides HBM); beta for t+1 precomputed at t; unroll x2.
struct QItem { float2 k, e, q; float v, b; };

__global__ __launch_bounds__(64) void kda_scan(
    const float* __restrict__ Q, const float* __restrict__ Kk,
    const float* __restrict__ V, const float* __restrict__ EG,
    const float* __restrict__ Braw, float* __restrict__ O)
{
    constexpr int T = 2048, H = 16, HD = 2048;
    const int bid = blockIdx.x;
    const int bh  = bid & 31;
    const int vg  = bid >> 5;          // 0..7
    const int b = bh >> 4, hh = bh & 15;
    const int lane = threadIdx.x;
    const int col  = lane >> 2;        // 0..15
    const int sl   = lane & 3;         // 0..3
    const int vcol = vg * 16 + col;

    __shared__ __align__(16) float kb_s[2][128];
    __shared__ __align__(16) float eb_s[2][128];
    __shared__ __align__(16) float qb_s[2][128];

    float s[32];
#pragma unroll
    for (int i = 0; i < 32; ++i) s[i] = 0.f;

    const size_t tok0 = (size_t)b * T;
    const int cb = hh * 128;
    const float* qp = Q  + tok0 * HD + cb;
    const float* kp = Kk + tok0 * HD + cb;
    const float* ep = EG + tok0 * HD + cb;
    const float* vp = V  + tok0 * HD + cb;
    const float* bp = Braw + tok0 * H + hh;
    float* op = O + tok0 * HD + cb;

    const int d0 = 2 * lane;
    const int cw = lane >> 1;
    const int pw = cw ^ (cw >> 3);
    const int stpos = pw * 4 + (d0 & 3);

    int rof[8];
#pragma unroll
    for (int j = 0; j < 8; ++j) rof[j] = (((sl << 3) + j) ^ sl) << 2;

    // prologue: t=0 -> LDS[0]; queue Qa=t1, Qb=t2; rv/beta for t=0
    *(float2*)&kb_s[0][stpos] = *(const float2*)&kp[d0];
    *(float2*)&eb_s[0][stpos] = *(const float2*)&ep[d0];
    *(float2*)&qb_s[0][stpos] = *(const float2*)&qp[d0];
    float rv   = vp[vcol];
    float beta = 1.f / (1.f + __expf(-bp[0]));

    QItem Qa, Qb2;
    Qa.k  = *(const float2*)&kp[(size_t)1 * HD + d0];
    Qa.e  = *(const float2*)&ep[(size_t)1 * HD + d0];
    Qa.q  = *(const float2*)&qp[(size_t)1 * HD + d0];
    Qa.v  = vp[(size_t)1 * HD + vcol];
    Qa.b  = bp[(size_t)1 * H];
    Qb2.k = *(const float2*)&kp[(size_t)2 * HD + d0];
    Qb2.e = *(const float2*)&ep[(size_t)2 * HD + d0];
    Qb2.q = *(const float2*)&qp[(size_t)2 * HD + d0];
    Qb2.v = vp[(size_t)2 * HD + vcol];
    Qb2.b = bp[(size_t)2 * H];

    auto step = [&](const int t, const int cur, QItem& Qw) {
        const int nxt = cur ^ 1;
        // 1) stage t+1 (held in Qw) into the other LDS buffer
        *(float2*)&kb_s[nxt][stpos] = Qw.k;
        *(float2*)&eb_s[nxt][stpos] = Qw.e;
        *(float2*)&qb_s[nxt][stpos] = Qw.q;
        // 2) next-step v / beta (exp off the critical path)
        const float nv    = Qw.v;
        const float nbeta = 1.f / (1.f + __expf(-Qw.b));
        // 3) refill Qw with t+3 (clamped address; values unused past end)
        {
            const int tc = (t + 3 < T) ? (t + 3) : (T - 1);
            const size_t o3 = (size_t)tc * HD;
            Qw.k = *(const float2*)&kp[o3 + d0];
            Qw.e = *(const float2*)&ep[o3 + d0];
            Qw.q = *(const float2*)&qp[o3 + d0];
            Qw.v = vp[o3 + vcol];
            Qw.b = bp[(size_t)tc * H];
        }
        // 4) batched LDS reads for step t
        float4 er[8], kr[8], qr[8];
#pragma unroll
        for (int j = 0; j < 8; ++j) {
            er[j] = *(const float4*)&eb_s[cur][rof[j]];
            kr[j] = *(const float4*)&kb_s[cur][rof[j]];
            qr[j] = *(const float4*)&qb_s[cur][rof[j]];
        }
        // 5) pass 1: decay + in-slice k.s
        float a0 = 0.f, a1 = 0.f, a2 = 0.f, a3 = 0.f;
#pragma unroll
        for (int j = 0; j < 8; ++j) {
            float s0 = s[4 * j + 0] * er[j].x, s1 = s[4 * j + 1] * er[j].y;
            float s2 = s[4 * j + 2] * er[j].z, s3 = s[4 * j + 3] * er[j].w;
            s[4 * j + 0] = s0; s[4 * j + 1] = s1;
            s[4 * j + 2] = s2; s[4 * j + 3] = s3;
            a0 = fmaf(kr[j].x, s0, a0); a1 = fmaf(kr[j].y, s1, a1);
            a2 = fmaf(kr[j].z, s2, a2); a3 = fmaf(kr[j].w, s3, a3);
        }
        float kS = (a0 + a1) + (a2 + a3);
        kS = qadd1(kS);
        kS = qadd2(kS);
        const float delta = beta * (rv - kS);
        // 6) pass 2: rank-1 update + in-slice q.s
        float o0 = 0.f, o1 = 0.f, o2v = 0.f, o3 = 0.f;
#pragma unroll
        for (int j = 0; j < 8; ++j) {
            float s0 = fmaf(kr[j].x, delta, s[4 * j + 0]);
            float s1 = fmaf(kr[j].y, delta, s[4 * j + 1]);
            float s2 = fmaf(kr[j].z, delta, s[4 * j + 2]);
            float s3 = fmaf(kr[j].w, delta, s[4 * j + 3]);
            s[4 * j + 0] = s0; s[4 * j + 1] = s1;
            s[4 * j + 2] = s2; s[4 * j + 3] = s3;
            o0 = fmaf(qr[j].x, s0, o0); o1 = fmaf(qr[j].y, s1, o1);
            o2v = fmaf(qr[j].z, s2, o2v); o3 = fmaf(qr[j].w, s3, o3);
        }
        float oo = (o0 + o1) + (o2v + o3);
        oo = qadd1(oo);
        oo = qadd2(oo);
        if (sl == 0) op[(size_t)t * HD + vcol] = oo;
        rv = nv; beta = nbeta;
    };

    for (int t = 0; t < T; t += 2) {
        step(t, 0, Qa);
        step(t + 1, 1, Qb2);
    }
}

// ------ gated RMSNorm: obf16 = rms(o)*norm_w*sigmoid(gate), bf16 out --------
__global__ __launch_bounds__(256) void norm_gate(
    const float* __restrict__ O, const float* __restrict__ Gate,
    const float* __restrict__ norm_w, ushort* __restrict__ Out16, int rows)
{
    const int wave = threadIdx.x >> 6;
    const int lane = threadIdx.x & 63;
    const int row  = blockIdx.x * 4 + wave;
    if (row >= rows) return;
    const size_t base = (size_t)row * 128;

    float o0 = O[base + lane], o1 = O[base + 64 + lane];
    float ss = o0 * o0 + o1 * o1;
#pragma unroll
    for (int off = 32; off >= 1; off >>= 1) ss += __shfl_xor(ss, off);
    const float scale = rsqrtf(ss * (1.f / 128.f) + 1e-6f);

    const float g0 = Gate[base + lane], g1 = Gate[base + 64 + lane];
    o0 = o0 * scale * norm_w[lane]      * (1.f / (1.f + __expf(-g0)));
    o1 = o1 * scale * norm_w[64 + lane] * (1.f / (1.f + __expf(-g1)));
    Out16[base + lane]      = f2bf(o0);
    Out16[base + 64 + lane] = f2bf(o1);
}

// ---------------------------------------------------------------------------
extern "C" void kernel_launch(void* const* d_in, const int* in_sizes, int n_in,
                              void* d_out, int out_size, void* d_ws, size_t ws_size,
                              hipStream_t stream)
{
    const float* h    = (const float*)d_in[0];
    const float* Wq   = (const float*)d_in[1];
    const float* Wk   = (const float*)d_in[2];
    const float* Wv   = (const float*)d_in[3];
    const float* cwq  = (const float*)d_in[4];
    const float* cwk  = (const float*)d_in[5];
    const float* cwv  = (const float*)d_in[6];
    const float* A_log= (const float*)d_in[7];
    const float* dtb  = (const float*)d_in[8];
    const float* Wfa  = (const float*)d_in[9];
    const float* Wfb  = (const float*)d_in[10];
    const float* Wb   = (const float*)d_in[11];
    const float* Wga  = (const float*)d_in[12];
    const float* Wgb  = (const float*)d_in[13];
    const float* nw   = (const float*)d_in[14];
    const float* Wo   = (const float*)d_in[15];
    float* out = (float*)d_out;

    const int M = 4096, HID = 2048;
    const size_t big = (size_t)M * HID;        // 8M elements
    float* ws    = (float*)d_ws;
    float* qb    = ws;          // post-scan: gateb
    float* kb    = qb + big;
    float* vb    = kb + big;    // post-norm: obb16 (ushort)
    float* gb    = vb + big;
    float* ob    = gb + big;
    float* betab = ob + big;                        // 4096x16
    float* halb  = betab + (size_t)M * 16;          // 110592
    ushort* hb16 = (ushort*)(halb + 110592);        // [M,HID] bf16
    ushort* wqT  = hb16 + big;                      // [2048,2048] bf16 (x4)
    ushort* wkT  = wqT + (size_t)HID * HID;
    ushort* wvT  = wkT + (size_t)HID * HID;
    ushort* wfT  = wvT + (size_t)HID * HID;
    ushort* tfbT = wfT + (size_t)HID * HID;         // [2048,128] bf16
    ushort* wfa16= tfbT + (size_t)HID * 128;        // [2048,128] bf16

    float*  gateb = qb;
    ushort* obb16 = (ushort*)vb;

    dim3 blk(256);

    // bf16 casts / transposes
    cast_bf16<<<dim3(4096), blk, 0, stream>>>(h, hb16, (int)(big / 8));
    tcast<<<dim3(32, 32), blk, 0, stream>>>(Wq, wqT, HID, HID);
    tcast<<<dim3(32, 32), blk, 0, stream>>>(Wk, wkT, HID, HID);
    tcast<<<dim3(32, 32), blk, 0, stream>>>(Wv, wvT, HID, HID);

    // compose Wf = Wfa@Wfb in bf16 MFMA: wfT[m,n] = sum_k Wfb[k,m]*Wfa[n,k]
    tcast<<<dim3(32, 2), blk, 0, stream>>>(Wfb, tfbT, 128, HID);
    cast_bf16<<<dim3(128), blk, 0, stream>>>(Wfa, wfa16, (int)((size_t)HID * 128 / 8));
    gemm_bf16<true><<<dim3(16, 16, 1), blk, 0, stream>>>(
        tfbT, tfbT, tfbT, tfbT, wfa16, wfa16, wfa16, wfa16,
        wfT, wfT, wfT, wfT, HID, HID, 128);

    // q,k,v,g projections in ONE launch
    gemm_bf16<false><<<dim3(32, 16, 4), blk, 0, stream>>>(
        hb16, hb16, hb16, hb16, wqT, wkT, wvT, wfT,
        qb, kb, vb, gb, M, HID, HID);

    // beta
    gemm_n16<<<dim3(M / 16), blk, 0, stream>>>(h, Wb, betab, M, HID);

    // conv + SiLU (segmented, race-free via halo snapshot)
    halo_save<<<dim3(432), blk, 0, stream>>>(qb, kb, vb, halb);
    conv_silu<<<dim3(192), blk, 0, stream>>>(qb, kb, vb, cwq, cwk, cwv, halb);

    // l2norm q/k, g -> exp(g)
    prep_qkg<<<dim3(16384), blk, 0, stream>>>(qb, kb, gb, A_log, dtb, M * 16);

    // gated delta-rule scan
    kda_scan<<<dim3(256), dim3(64), 0, stream>>>(qb, kb, vb, gb, betab, ob);

    // gate path: compose Wg = Wga@Wgb (bf16 MFMA, reuse small scratch + wqT)
    tcast<<<dim3(32, 2), blk, 0, stream>>>(Wgb, tfbT, 128, HID);
    cast_bf16<<<dim3(128), blk, 0, stream>>>(Wga, wfa16, (int)((size_t)HID * 128 / 8));
    gemm_bf16<true><<<dim3(16, 16, 1), blk, 0, stream>>>(
        tfbT, tfbT, tfbT, tfbT, wfa16, wfa16, wfa16, wfa16,
        wqT, wqT, wqT, wqT, HID, HID, 128);
    gemm_bf16<false><<<dim3(32, 16, 1), blk, 0, stream>>>(
        hb16, hb16, hb16, hb16, wqT, wqT, wqT, wqT,
        gateb, gateb, gateb, gateb, M, HID, HID);

    // gated RMSNorm -> bf16 (fused cast)
    norm_gate<<<dim3(16384), blk, 0, stream>>>(ob, gateb, nw, obb16, M * 16);

    // output projection
    tcast<<<dim3(32, 32), blk, 0, stream>>>(Wo, wkT, HID, HID);
    gemm_bf16<false><<<dim3(32, 16, 1), blk, 0, stream>>>(
        obb16, obb16, obb16, obb16, wkT, wkT, wkT, wkT,
        out, out, out, out, M, HID, HID);
}